// Round 4
// baseline (75.032 us; speedup 1.0000x reference)
//
#include <hip/hip_runtime.h>

#define NUM_IND 1000

typedef float f4 __attribute__((ext_vector_type(4)));

// ONE fused kernel. Each block:
//  1) builds the full 1000x32 lookup table in LDS (thread t -> industry t):
//     table[t] = relu(vars[t]@W1+b1)@W2 + b2 + 0.1*emb[t]   (~1-2 us, once)
//  2) grid-strides the gather: out[g] = table[idx[g>>3]] chunk (g&7),
//     reading the table from LDS (ds_read_b128) instead of L1/L2 scatter.
// 1024 threads, 128000 B LDS -> 1 block/CU, 16 waves/CU. Stores are the
// same fully-coalesced 16B/lane stream the 7 TB/s fill kernel uses.
__global__ __launch_bounds__(1024) void fused_encoder_kernel(
    const int*   __restrict__ idx,   // [B]
    const float* __restrict__ vars,  // [1000,8]
    const float* __restrict__ W1,    // [8,16]
    const float* __restrict__ b1,    // [16]
    const float* __restrict__ W2,    // [16,32]
    const float* __restrict__ b2,    // [32]
    const float* __restrict__ emb,   // [1000,32]
    f4*          __restrict__ out4,  // [B*8]
    int total4)                      // B*8
{
    __shared__ __align__(16) float table[NUM_IND][32];   // 128,000 B

    const int tid = threadIdx.x;

    // ---- build phase: thread t computes industry t's 32 outputs ----
    if (tid < NUM_IND) {
        float v[8];
#pragma unroll
        for (int k = 0; k < 8; ++k) v[k] = vars[tid * 8 + k];

        float h[16];
#pragma unroll
        for (int j = 0; j < 16; ++j) {
            float acc = b1[j];
#pragma unroll
            for (int k = 0; k < 8; ++k) acc = fmaf(v[k], W1[k * 16 + j], acc);
            h[j] = fmaxf(acc, 0.0f);
        }

#pragma unroll
        for (int j = 0; j < 32; ++j) {
            float acc = b2[j];
#pragma unroll
            for (int k = 0; k < 16; ++k) acc = fmaf(h[k], W2[k * 32 + j], acc);
            table[tid][j] = acc + 0.1f * emb[tid * 32 + j];
        }
    }
    __syncthreads();

    // ---- gather phase: one f4 per (thread, iteration), grid-stride ----
    const f4* table4 = (const f4*)&table[0][0];   // [1000*8] 16B chunks
    const int stride = gridDim.x * blockDim.x;
    for (int g = blockIdx.x * blockDim.x + tid; g < total4; g += stride) {
        const int id = idx[g >> 3];               // 8 lanes share one idx line
        out4[g] = table4[id * 8 + (g & 7)];       // LDS ds_read_b128
    }
}

extern "C" void kernel_launch(void* const* d_in, const int* in_sizes, int n_in,
                              void* d_out, int out_size, void* d_ws, size_t ws_size,
                              hipStream_t stream) {
    const int*   idx  = (const int*)  d_in[0];  // [B] int32
    const float* vars = (const float*)d_in[1];  // [1000,8]
    const float* W1   = (const float*)d_in[2];  // [8,16]
    const float* b1   = (const float*)d_in[3];  // [16]
    const float* W2   = (const float*)d_in[4];  // [16,32]
    const float* b2   = (const float*)d_in[5];  // [32]
    const float* emb  = (const float*)d_in[6];  // [1000,32]

    f4* out4 = (f4*)d_out;                      // [B*8] 16B chunks
    const int B = in_sizes[0];
    const int total4 = B * 8;                   // 16,777,216 for B=2^21

    // 256 blocks x 1024 threads = 1 block/CU (LDS-bound), 64 iters/thread.
    fused_encoder_kernel<<<256, 1024, 0, stream>>>(idx, vars, W1, b1, W2, b2,
                                                   emb, out4, total4);
}

// Round 5
// 62.853 us; speedup vs baseline: 1.1938x; 1.1938x over previous
//
#include <hip/hip_runtime.h>

#define NUM_IND 1000
#define ROWPAD  40   // floats per padded LDS row (160 B): bank base = 8*(id&3)

typedef float f4 __attribute__((ext_vector_type(4)));

// ONE fused kernel, 1024 threads x 256 blocks (1 block/CU, 16 waves).
// Phase 1: build padded 1000x40 table in LDS (thread t -> industry t).
// Phase 2: macro-gather. Per wave, per macro (512 f4-chunks = 64 examples):
//   - 64 idx loaded in ONE coalesced 256B load, PREFETCHED one macro ahead
//   - 8 iterations: __shfl distributes idx -> padded ds_read_b128 -> store
//   - stores: 64 lanes x 16B = contiguous 1KB per instruction
__global__ __launch_bounds__(1024) void fused_encoder_kernel(
    const int*   __restrict__ idx,   // [B]
    const float* __restrict__ vars,  // [1000,8]
    const float* __restrict__ W1,    // [8,16]
    const float* __restrict__ b1,    // [16]
    const float* __restrict__ W2,    // [16,32]
    const float* __restrict__ b2,    // [32]
    const float* __restrict__ emb,   // [1000,32]
    f4*          __restrict__ out4,  // [B*8]
    int nmacros,                     // total4 / 512
    int total4)                      // B*8
{
    __shared__ __align__(16) float table[NUM_IND * ROWPAD];  // 160,000 B

    const int tid  = threadIdx.x;
    const int lane = tid & 63;

    // global wave id / stride, in macro units
    const int wave  = blockIdx.x * (blockDim.x >> 6) + (tid >> 6);
    const int wstep = gridDim.x * (blockDim.x >> 6);

    // ---- prefetch first macro's idx BEFORE the build (hides under MLP) ----
    int m = wave;
    int id_next = (m < nmacros) ? idx[m * 64 + lane] : 0;

    // ---- build phase: thread t computes industry t's 32 outputs ----
    if (tid < NUM_IND) {
        float v[8];
#pragma unroll
        for (int k = 0; k < 8; ++k) v[k] = vars[tid * 8 + k];

        float h[16];
#pragma unroll
        for (int j = 0; j < 16; ++j) {
            float acc = b1[j];
#pragma unroll
            for (int k = 0; k < 8; ++k) acc = fmaf(v[k], W1[k * 16 + j], acc);
            h[j] = fmaxf(acc, 0.0f);
        }

        const f4* embrow = (const f4*)(emb + tid * 32);
        f4* tabrow = (f4*)(table + tid * ROWPAD);
#pragma unroll
        for (int r = 0; r < 8; ++r) {             // 8 f4 chunks of 32 outputs
            const f4 e = embrow[r];
            f4 o;
#pragma unroll
            for (int q = 0; q < 4; ++q) {
                const int j = r * 4 + q;
                float acc = b2[j];
#pragma unroll
                for (int k = 0; k < 16; ++k) acc = fmaf(h[k], W2[k * 32 + j], acc);
                o[q] = acc + 0.1f * e[q];
            }
            tabrow[r] = o;
        }
    }
    __syncthreads();

    const f4* tab4 = (const f4*)table;            // padded: row stride 10 f4

    // ---- macro-gather loop ----
    for (; m < nmacros; m += wstep) {
        const int v_id = id_next;
        const int mn = m + wstep;
        if (mn < nmacros) id_next = idx[mn * 64 + lane];   // prefetch next

        const int base = m * 512 + lane;
#pragma unroll
        for (int c = 0; c < 8; ++c) {
            // lane serves chunk c*64+lane -> example 8c + (lane>>3) of macro
            const int id = __shfl(v_id, 8 * c + (lane >> 3), 64);
            out4[base + c * 64] = tab4[id * (ROWPAD / 4) + (lane & 7)];
        }
    }

    // ---- generic tail (B % 64 != 0); empty for B = 2^21 ----
    if (blockIdx.x == 0 && (tid >> 6) == 0) {
        for (int g = nmacros * 512 + lane; g < total4; g += 64) {
            const int id = idx[g >> 3];
            out4[g] = tab4[id * (ROWPAD / 4) + (g & 7)];
        }
    }
}

extern "C" void kernel_launch(void* const* d_in, const int* in_sizes, int n_in,
                              void* d_out, int out_size, void* d_ws, size_t ws_size,
                              hipStream_t stream) {
    const int*   idx  = (const int*)  d_in[0];  // [B] int32
    const float* vars = (const float*)d_in[1];  // [1000,8]
    const float* W1   = (const float*)d_in[2];  // [8,16]
    const float* b1   = (const float*)d_in[3];  // [16]
    const float* W2   = (const float*)d_in[4];  // [16,32]
    const float* b2   = (const float*)d_in[5];  // [32]
    const float* emb  = (const float*)d_in[6];  // [1000,32]

    f4* out4 = (f4*)d_out;                      // [B*8] 16B chunks
    const int B = in_sizes[0];
    const int total4  = B * 8;                  // 16,777,216 for B=2^21
    const int nmacros = total4 / 512;           // 32,768

    fused_encoder_kernel<<<256, 1024, 0, stream>>>(idx, vars, W1, b1, W2, b2,
                                                   emb, out4, nmacros, total4);
}

// Round 6
// 56.814 us; speedup vs baseline: 1.3207x; 1.1063x over previous
//
#include <hip/hip_runtime.h>

#define NUM_IND 1000
#define ROWPAD  40   // floats per padded LDS row (160 B): bank base = 8*(id&3)

typedef float f4 __attribute__((ext_vector_type(4)));

// ONE fused kernel, 1024 threads x 256 blocks (1 block/CU, 16 waves).
// Phase 1: build padded 1000x40 table in LDS (thread t -> industry t).
// Phase 2: gather with CONTIGUOUS per-wave output spans (fill-like DRAM
// page locality): wave w owns pairs [w*ppw, (w+1)*ppw), each pair = 2
// macros = 128 examples = 16 KB of contiguous ascending output.
// Idx is prefetched ONE PAIR (128 values, 2 coalesced 256B loads) ahead.
__global__ __launch_bounds__(1024) void fused_encoder_kernel(
    const int*   __restrict__ idx,   // [B]
    const float* __restrict__ vars,  // [1000,8]
    const float* __restrict__ W1,    // [8,16]
    const float* __restrict__ b1,    // [16]
    const float* __restrict__ W2,    // [16,32]
    const float* __restrict__ b2,    // [32]
    const float* __restrict__ emb,   // [1000,32]
    f4*          __restrict__ out4,  // [B*8]
    int npairs,                      // (total4/512)/2
    int ppw,                         // ceil(npairs / nwaves)
    int total4)                      // B*8
{
    __shared__ __align__(16) float table[NUM_IND * ROWPAD];  // 160,000 B

    const int tid  = threadIdx.x;
    const int lane = tid & 63;
    const int wave = blockIdx.x * (blockDim.x >> 6) + (tid >> 6);

    const int pbeg = wave * ppw;
    const int pend = min(pbeg + ppw, npairs);

    // ---- prefetch first pair's 128 idx BEFORE the build (hides under MLP) ----
    int a0 = 0, a1 = 0;
    if (pbeg < pend) {
        a0 = idx[(pbeg * 2 + 0) * 64 + lane];
        a1 = idx[(pbeg * 2 + 1) * 64 + lane];
    }

    // ---- build phase: thread t computes industry t's 32 outputs ----
    if (tid < NUM_IND) {
        float v[8];
#pragma unroll
        for (int k = 0; k < 8; ++k) v[k] = vars[tid * 8 + k];

        float h[16];
#pragma unroll
        for (int j = 0; j < 16; ++j) {
            float acc = b1[j];
#pragma unroll
            for (int k = 0; k < 8; ++k) acc = fmaf(v[k], W1[k * 16 + j], acc);
            h[j] = fmaxf(acc, 0.0f);
        }

        const f4* embrow = (const f4*)(emb + tid * 32);
        f4* tabrow = (f4*)(table + tid * ROWPAD);
#pragma unroll
        for (int r = 0; r < 8; ++r) {             // 8 f4 chunks of 32 outputs
            const f4 e = embrow[r];
            f4 o;
#pragma unroll
            for (int q = 0; q < 4; ++q) {
                const int j = r * 4 + q;
                float acc = b2[j];
#pragma unroll
                for (int k = 0; k < 16; ++k) acc = fmaf(h[k], W2[k * 32 + j], acc);
                o[q] = acc + 0.1f * e[q];
            }
            tabrow[r] = o;
        }
    }
    __syncthreads();

    const f4* tab4 = (const f4*)table;            // padded: row stride 10 f4

    // ---- pair loop: contiguous ascending 16 KB per pair per wave ----
    for (int p = pbeg; p < pend; ++p) {
        int n0 = 0, n1 = 0;
        const bool more = (p + 1 < pend);
        if (more) {                               // prefetch next pair early
            n0 = idx[((p + 1) * 2 + 0) * 64 + lane];
            n1 = idx[((p + 1) * 2 + 1) * 64 + lane];
        }
        {   // macro 2p
            const int base = (2 * p) * 512 + lane;
#pragma unroll
            for (int c = 0; c < 8; ++c) {
                const int id = __shfl(a0, 8 * c + (lane >> 3), 64);
                out4[base + c * 64] = tab4[id * (ROWPAD / 4) + (lane & 7)];
            }
        }
        {   // macro 2p+1
            const int base = (2 * p + 1) * 512 + lane;
#pragma unroll
            for (int c = 0; c < 8; ++c) {
                const int id = __shfl(a1, 8 * c + (lane >> 3), 64);
                out4[base + c * 64] = tab4[id * (ROWPAD / 4) + (lane & 7)];
            }
        }
        a0 = n0; a1 = n1;
    }

    // ---- generic tail (elements beyond full pairs); empty for B = 2^21 ----
    if (blockIdx.x == 0 && tid < 64) {
        for (int g = npairs * 1024 + lane; g < total4; g += 64) {
            const int id = idx[g >> 3];
            out4[g] = tab4[id * (ROWPAD / 4) + (g & 7)];
        }
    }
}

extern "C" void kernel_launch(void* const* d_in, const int* in_sizes, int n_in,
                              void* d_out, int out_size, void* d_ws, size_t ws_size,
                              hipStream_t stream) {
    const int*   idx  = (const int*)  d_in[0];  // [B] int32
    const float* vars = (const float*)d_in[1];  // [1000,8]
    const float* W1   = (const float*)d_in[2];  // [8,16]
    const float* b1   = (const float*)d_in[3];  // [16]
    const float* W2   = (const float*)d_in[4];  // [16,32]
    const float* b2   = (const float*)d_in[5];  // [32]
    const float* emb  = (const float*)d_in[6];  // [1000,32]

    f4* out4 = (f4*)d_out;                      // [B*8] 16B chunks
    const int B = in_sizes[0];
    const int total4  = B * 8;                  // 16,777,216 for B=2^21
    const int nmacros = total4 / 512;           // 32,768
    const int npairs  = nmacros / 2;            // 16,384

    const int blocks = 256, threads = 1024;
    const int nwaves = blocks * (threads / 64); // 4096
    const int ppw    = (npairs + nwaves - 1) / nwaves;  // 4 for B=2^21

    fused_encoder_kernel<<<blocks, threads, 0, stream>>>(idx, vars, W1, b1, W2,
                                                         b2, emb, out4,
                                                         npairs, ppw, total4);
}